// Round 3
// baseline (352.531 us; speedup 1.0000x reference)
//
#include <hip/hip_runtime.h>
#include <math.h>

#define D 512
#define K 14
#define EPS 1e-8f
#define NROWS 65536

// Output float offsets (reference tuple order, flattened)
#define O_SNN       0          // 16*4096
#define O_PHINA     65536      // 16*4096*13
#define O_SAN       917504     // 16*4096
#define O_SAA       983040     // 16*4096
#define O_PHIOTHER  1048576    // 16*4096*12
#define O_SAANORM   1835008    // 16*4096
#define O_PSEUDO    1900544    // 16*4096
#define O_SCORES    1966080    // 16*4096
#define O_TN        2031616    // 512

__device__ __forceinline__ float wave_sum(float v) {
    v += __shfl_xor(v, 1);
    v += __shfl_xor(v, 2);
    v += __shfl_xor(v, 4);
    v += __shfl_xor(v, 8);
    v += __shfl_xor(v, 16);
    v += __shfl_xor(v, 32);
    return v;
}
__device__ __forceinline__ float wave_min(float v) {
    v = fminf(v, __shfl_xor(v, 1));
    v = fminf(v, __shfl_xor(v, 2));
    v = fminf(v, __shfl_xor(v, 4));
    v = fminf(v, __shfl_xor(v, 8));
    v = fminf(v, __shfl_xor(v, 16));
    v = fminf(v, __shfl_xor(v, 32));
    return v;
}
__device__ __forceinline__ float wave_max(float v) {
    v = fmaxf(v, __shfl_xor(v, 1));
    v = fmaxf(v, __shfl_xor(v, 2));
    v = fmaxf(v, __shfl_xor(v, 4));
    v = fmaxf(v, __shfl_xor(v, 8));
    v = fmaxf(v, __shfl_xor(v, 16));
    v = fmaxf(v, __shfl_xor(v, 32));
    return v;
}

// Kernel A: normalize T_emb rows 0..13 into W[0..13], copy w_score into W[14],
// and write T_n_enhanced (= normalized T_emb[13]) to output. 15 waves.
__global__ __launch_bounds__(960) void kprep(const float* __restrict__ T_emb,
                                             const float* __restrict__ w_score,
                                             float* __restrict__ W,
                                             float* __restrict__ tn_out) {
    int lane = threadIdx.x & 63;
    int w = threadIdx.x >> 6; // 0..14
    float4* W4 = (float4*)W;
    if (w < K) {
        const float4* src = (const float4*)T_emb + w * 128;
        float4 a = src[lane];
        float4 b = src[64 + lane];
        float ss = a.x * a.x + a.y * a.y + a.z * a.z + a.w * a.w
                 + b.x * b.x + b.y * b.y + b.z * b.z + b.w * b.w;
        ss = wave_sum(ss);
        float inv = 1.0f / (sqrtf(ss) + EPS);
        float4 na = make_float4(a.x * inv, a.y * inv, a.z * inv, a.w * inv);
        float4 nb = make_float4(b.x * inv, b.y * inv, b.z * inv, b.w * inv);
        W4[w * 128 + lane] = na;
        W4[w * 128 + 64 + lane] = nb;
        if (w == K - 1) {
            float4* t4 = (float4*)tn_out;
            t4[lane] = na;
            t4[64 + lane] = nb;
        }
    } else {
        const float4* src = (const float4*)w_score;
        W4[14 * 128 + lane] = src[lane];
        W4[14 * 128 + 64 + lane] = src[64 + lane];
    }
}

// Dots kernel: each lane owns one row; all lanes walk the same k (wave-uniform),
// so W reads go through the scalar pipe (s_load). Zero cross-lane ops.
// gridDim.x = 256 row-groups (256 rows each), gridDim.y = 2 K-halves.
// Writes partial dot matrix: wsd[half][row][16].
template<int NK>
__global__ __launch_bounds__(256) void kdots(const float4* __restrict__ feats,
                                             const float4* __restrict__ W4,
                                             float* __restrict__ wsd) {
    const int lane = threadIdx.x & 63;
    const int wid  = threadIdx.x >> 6;
    const int row  = blockIdx.x * 256 + wid * 64 + lane;
    const int half = blockIdx.y;      // 0 or 1
    const int kb   = half * 64;       // float4-index base of this K-half

    const float4* fp = feats + (size_t)row * 128 + kb;
    const float4* tp = W4 + kb;

    float acc[NK];
#pragma unroll
    for (int j = 0; j < NK; j++) acc[j] = 0.0f;

#pragma unroll 4
    for (int s = 0; s < 64; s++) {
        float4 f = fp[s];
        int su = __builtin_amdgcn_readfirstlane(s); // force uniform -> s_load for W
#pragma unroll
        for (int j = 0; j < NK; j++) {
            float4 t = tp[j * 128 + su];
            acc[j] = fmaf(f.x, t.x, fmaf(f.y, t.y, fmaf(f.z, t.z, fmaf(f.w, t.w, acc[j]))));
        }
    }

    float4* o = (float4*)(wsd + ((size_t)half * NROWS + row) * 16);
    o[0] = make_float4(acc[0], acc[1], acc[2],  acc[3]);
    o[1] = make_float4(acc[4], acc[5], acc[6],  acc[7]);
    o[2] = make_float4(acc[8], acc[9], acc[10], acc[11]);
    o[3] = make_float4(acc[12], acc[13], (NK > 14) ? acc[14] : 0.0f, 0.0f);
}

// Postprocess normal: combine K-halves, scatter to phi_na / S_nn.
__global__ __launch_bounds__(256) void kpostN(const float* __restrict__ wsd,
                                              float* __restrict__ S_nn,
                                              float* __restrict__ phi_na) {
    int i = blockIdx.x * 256 + threadIdx.x;   // over NROWS*16
    int row = i >> 4, j = i & 15;
    float v = wsd[i] + wsd[NROWS * 16 + i];
    if (j < 13)       phi_na[row * 13 + j] = v;
    else if (j == 13) S_nn[row] = v;
}

// Postprocess anomaly: combine K-halves, gather true class, scatter others,
// sigmoid for scores.
__global__ __launch_bounds__(256) void kpostA(const float* __restrict__ wsd,
                                              const int* __restrict__ cls,
                                              const float* __restrict__ b_score,
                                              float* __restrict__ S_an,
                                              float* __restrict__ S_aa,
                                              float* __restrict__ phi_other,
                                              float* __restrict__ scores) {
    int i = blockIdx.x * 256 + threadIdx.x;   // over NROWS*16
    int row = i >> 4, j = i & 15;
    float v = wsd[i] + wsd[NROWS * 16 + i];
    int ci = cls[row >> 12];
    if (j < 13) {
        if (j == ci) S_aa[row] = v;
        else         phi_other[row * 12 + ((j < ci) ? j : j - 1)] = v;
    } else if (j == 13) {
        S_an[row] = v;
    } else if (j == 14) {
        scores[row] = 1.0f / (1.0f + expf(-(v + b_score[0])));
    }
}

// Per-batch min/max of S_aa_true and S_an. One block per batch.
__global__ __launch_bounds__(256) void kminmax(const float* __restrict__ S_aa,
                                               const float* __restrict__ S_an,
                                               float* __restrict__ mm) {
    int b = blockIdx.x;
    int t = threadIdx.x;
    int lane = t & 63, wid = t >> 6;
    const float* pa = S_aa + b * 4096;
    const float* pn = S_an + b * 4096;
    float mnA = 1e30f, mxA = -1e30f, mnN = 1e30f, mxN = -1e30f;
    for (int i = t; i < 4096; i += 256) {
        float a = pa[i];
        float n = pn[i];
        mnA = fminf(mnA, a); mxA = fmaxf(mxA, a);
        mnN = fminf(mnN, n); mxN = fmaxf(mxN, n);
    }
    mnA = wave_min(mnA); mxA = wave_max(mxA);
    mnN = wave_min(mnN); mxN = wave_max(mxN);
    __shared__ float red[4][4];
    if (lane == 0) {
        red[wid][0] = mnA; red[wid][1] = mxA;
        red[wid][2] = mnN; red[wid][3] = mxN;
    }
    __syncthreads();
    if (t == 0) {
        float a0 = red[0][0], a1 = red[0][1], a2 = red[0][2], a3 = red[0][3];
        for (int w = 1; w < 4; w++) {
            a0 = fminf(a0, red[w][0]); a1 = fmaxf(a1, red[w][1]);
            a2 = fminf(a2, red[w][2]); a3 = fmaxf(a3, red[w][3]);
        }
        mm[b * 4 + 0] = a0; mm[b * 4 + 1] = a1;
        mm[b * 4 + 2] = a2; mm[b * 4 + 3] = a3;
    }
}

// Fuse -> S_aa_norm, pseudo_labels.
__global__ __launch_bounds__(256) void kfinal(const float* __restrict__ S_aa,
                                              const float* __restrict__ S_an,
                                              const float* __restrict__ mm,
                                              float* __restrict__ S_aa_norm,
                                              float* __restrict__ pseudo) {
    int i = blockIdx.x * 256 + threadIdx.x;
    if (i >= NROWS) return;
    int b = i >> 12;
    float mnA = mm[b * 4 + 0], mxA = mm[b * 4 + 1];
    float mnN = mm[b * 4 + 2], mxN = mm[b * 4 + 3];
    float s_aa = (S_aa[i] - mnA) / (mxA - mnA + EPS);
    float s_an = (S_an[i] - mnN) / (mxN - mnN + EPS);
    float fused = 0.8f * s_aa + 0.2f * (1.0f - s_an);
    pseudo[i] = fused > 0.55f ? 1.0f : 0.0f;
    S_aa_norm[i] = s_aa;
}

extern "C" void kernel_launch(void* const* d_in, const int* in_sizes, int n_in,
                              void* d_out, int out_size, void* d_ws, size_t ws_size,
                              hipStream_t stream) {
    const float* normal_feats  = (const float*)d_in[0];
    const float* anomaly_feats = (const float*)d_in[1];
    const int*   cls           = (const int*)d_in[2];
    const float* T_emb         = (const float*)d_in[3];
    const float* w_score       = (const float*)d_in[4];
    const float* b_score       = (const float*)d_in[5];
    float* out = (float*)d_out;

    float* W     = (float*)d_ws;                       // 15*512 floats (pad to 8192)
    float* mm    = (float*)d_ws + 8192;                // 64 floats
    float* dotsN = (float*)d_ws + 8192 + 64;           // 2*65536*16 floats (8 MB)
    float* dotsA = dotsN + 2 * NROWS * 16;             // 2*65536*16 floats (8 MB)

    kprep<<<1, 960, 0, stream>>>(T_emb, w_score, W, out + O_TN);

    dim3 gdots(256, 2);
    kdots<14><<<gdots, 256, 0, stream>>>((const float4*)normal_feats,
                                         (const float4*)W, dotsN);
    kpostN<<<(NROWS * 16) / 256, 256, 0, stream>>>(dotsN, out + O_SNN, out + O_PHINA);

    kdots<15><<<gdots, 256, 0, stream>>>((const float4*)anomaly_feats,
                                         (const float4*)W, dotsA);
    kpostA<<<(NROWS * 16) / 256, 256, 0, stream>>>(dotsA, cls, b_score,
                                                   out + O_SAN, out + O_SAA,
                                                   out + O_PHIOTHER, out + O_SCORES);

    kminmax<<<16, 256, 0, stream>>>(out + O_SAA, out + O_SAN, mm);

    kfinal<<<256, 256, 0, stream>>>(out + O_SAA, out + O_SAN, mm,
                                    out + O_SAANORM, out + O_PSEUDO);
}

// Round 5
// 346.601 us; speedup vs baseline: 1.0171x; 1.0171x over previous
//
#include <hip/hip_runtime.h>
#include <math.h>

#define D 512
#define K 14
#define EPS 1e-8f
#define NROWS 65536

// Output float offsets (reference tuple order, flattened)
#define O_SNN       0          // 16*4096
#define O_PHINA     65536      // 16*4096*13
#define O_SAN       917504     // 16*4096
#define O_SAA       983040     // 16*4096
#define O_PHIOTHER  1048576    // 16*4096*12
#define O_SAANORM   1835008    // 16*4096
#define O_PSEUDO    1900544    // 16*4096
#define O_SCORES    1966080    // 16*4096
#define O_TN        2031616    // 512

__device__ __forceinline__ float wave_sum(float v) {
    v += __shfl_xor(v, 1);  v += __shfl_xor(v, 2);  v += __shfl_xor(v, 4);
    v += __shfl_xor(v, 8);  v += __shfl_xor(v, 16); v += __shfl_xor(v, 32);
    return v;
}
__device__ __forceinline__ float wave_min(float v) {
    v = fminf(v, __shfl_xor(v, 1));  v = fminf(v, __shfl_xor(v, 2));
    v = fminf(v, __shfl_xor(v, 4));  v = fminf(v, __shfl_xor(v, 8));
    v = fminf(v, __shfl_xor(v, 16)); v = fminf(v, __shfl_xor(v, 32));
    return v;
}
__device__ __forceinline__ float wave_max(float v) {
    v = fmaxf(v, __shfl_xor(v, 1));  v = fmaxf(v, __shfl_xor(v, 2));
    v = fmaxf(v, __shfl_xor(v, 4));  v = fmaxf(v, __shfl_xor(v, 8));
    v = fmaxf(v, __shfl_xor(v, 16)); v = fmaxf(v, __shfl_xor(v, 32));
    return v;
}

// kprep: normalize T rows, build transposed table Wt[s][k] (s = float4 chunk
// 0..127, k = 0..14 where 14 = w_score), write T_n_enhanced. 15 waves.
__global__ __launch_bounds__(960) void kprep(const float* __restrict__ T_emb,
                                             const float* __restrict__ w_score,
                                             float4* __restrict__ Wt4,
                                             float* __restrict__ tn_out) {
    int lane = threadIdx.x & 63;
    int w = threadIdx.x >> 6; // 0..14
    if (w < K) {
        const float4* src = (const float4*)T_emb + w * 128;
        float4 a = src[lane];
        float4 b = src[64 + lane];
        float ss = a.x * a.x + a.y * a.y + a.z * a.z + a.w * a.w
                 + b.x * b.x + b.y * b.y + b.z * b.z + b.w * b.w;
        ss = wave_sum(ss);
        float inv = 1.0f / (sqrtf(ss) + EPS);
        float4 na = make_float4(a.x * inv, a.y * inv, a.z * inv, a.w * inv);
        float4 nb = make_float4(b.x * inv, b.y * inv, b.z * inv, b.w * inv);
        Wt4[lane * 15 + w] = na;
        Wt4[(64 + lane) * 15 + w] = nb;
        if (w == K - 1) {
            float4* t4 = (float4*)tn_out;
            t4[lane] = na;
            t4[64 + lane] = nb;
        }
    } else {
        const float4* src = (const float4*)w_score;
        Wt4[lane * 15 + 14] = src[lane];
        Wt4[(64 + lane) * 15 + 14] = src[64 + lane];
    }
}

// kdots: grid (1024, 2). blockIdx.y: 0 = normal feats, 1 = anomaly feats.
// Block = 4 waves, 64 rows. Wave w computes K-quarter [w*128, w*128+128) for
// all 64 rows (lane l owns row rbase+l). Staged through LDS in 32-float
// chunks with +4-dword row padding (conflict-free b128 read & write).
// T read via scalar pipe (readfirstlane-forced uniform index into Wt).
// Partials combined in LDS; epilogue scatters final outputs.
__global__ __launch_bounds__(256, 4) void kdots(const float4* __restrict__ nf4,
                                                const float4* __restrict__ af4,
                                                const float4* __restrict__ Wt4,
                                                const int* __restrict__ cls,
                                                const float* __restrict__ b_score,
                                                float* __restrict__ S_nn,
                                                float* __restrict__ phi_na,
                                                float* __restrict__ S_an,
                                                float* __restrict__ S_aa,
                                                float* __restrict__ phi_other,
                                                float* __restrict__ scores) {
    __shared__ float smem[9216];           // 4 waves * 64 rows * 36 dwords
    const int tid  = threadIdx.x;
    const int l    = tid & 63;
    const int w    = tid >> 6;             // K-quarter index 0..3
    const int rbase = blockIdx.x * 64;
    const bool anom = (blockIdx.y != 0);
    const float4* feats4 = anom ? af4 : nf4;

    float* sb = &smem[w * 2304];           // this wave's staging region

    // Staging addressing: iter j (0..7): lane l loads row (j*8 + l>>3),
    // float4 col (l&7) of the 32-float chunk.
    const int sr = l >> 3;
    const int sc = l & 7;
    const float4* gbase = feats4 + (size_t)(rbase + sr) * 128 + w * 32 + sc;
    // LDS write float-offset within wave region for (j, sr, sc):
    //   row (j*8+sr) at stride 36 floats + float4 col sc*4
    //   = j*288 + sr*36 + sc*4 = j*288 + wslot*4
    const int wslot = sr * 9 + sc;

    float4 g[8];
#pragma unroll
    for (int j = 0; j < 8; j++) g[j] = gbase[j * 1024];   // chunk 0

    float acc[15];
#pragma unroll
    for (int k = 0; k < 15; k++) acc[k] = 0.0f;

#pragma unroll 1
    for (int i = 0; i < 4; i++) {
        // commit staged chunk to LDS
#pragma unroll
        for (int j = 0; j < 8; j++)
            *(float4*)&sb[j * 288 + wslot * 4] = g[j];
        // prefetch next chunk (latency hidden by the FMA phase below)
        if (i < 3) {
#pragma unroll
            for (int j = 0; j < 8; j++) g[j] = gbase[j * 1024 + (i + 1) * 8];
        }
        // compute 8 float4 steps
#pragma unroll
        for (int s = 0; s < 8; s++) {
            float4 f = *(const float4*)&sb[l * 36 + s * 4];
            int su = __builtin_amdgcn_readfirstlane(w * 32 + i * 8 + s);
#pragma unroll
            for (int k = 0; k < 15; k++) {
                float4 t = Wt4[su * 15 + k];
                acc[k] = fmaf(f.x, t.x, fmaf(f.y, t.y,
                          fmaf(f.z, t.z, fmaf(f.w, t.w, acc[k]))));
            }
        }
    }

    // combine K-quarter partials via LDS (reuse staging storage)
    __syncthreads();
#pragma unroll
    for (int k = 0; k < 15; k++)
        smem[w * 1088 + l * 17 + k] = acc[k];
    __syncthreads();

    const float bsc = b_score[0];
    const int ci = anom ? cls[rbase >> 12] : 0;  // block-uniform
    for (int v = tid; v < 64 * 15; v += 256) {
        int r = v / 15;
        int j = v - r * 15;
        float s = smem[r * 17 + j] + smem[1088 + r * 17 + j]
                + smem[2176 + r * 17 + j] + smem[3264 + r * 17 + j];
        int row = rbase + r;
        if (!anom) {
            if (j < 13)       phi_na[row * 13 + j] = s;
            else if (j == 13) S_nn[row] = s;
        } else {
            if (j < 13) {
                if (j == ci) S_aa[row] = s;
                else         phi_other[row * 12 + ((j < ci) ? j : j - 1)] = s;
            } else if (j == 13) {
                S_an[row] = s;
            } else {
                scores[row] = 1.0f / (1.0f + expf(-(s + bsc)));
            }
        }
    }
}

// kbatch: fused per-batch minmax + normalize/fuse/threshold. 16 blocks.
__global__ __launch_bounds__(256) void kbatch(const float* __restrict__ S_aa,
                                              const float* __restrict__ S_an,
                                              float* __restrict__ S_aa_norm,
                                              float* __restrict__ pseudo) {
    int b = blockIdx.x;
    int t = threadIdx.x;
    int lane = t & 63, wid = t >> 6;
    const float* pa = S_aa + b * 4096;
    const float* pn = S_an + b * 4096;
    float mnA = 1e30f, mxA = -1e30f, mnN = 1e30f, mxN = -1e30f;
    for (int i = t; i < 4096; i += 256) {
        float a = pa[i];
        float n = pn[i];
        mnA = fminf(mnA, a); mxA = fmaxf(mxA, a);
        mnN = fminf(mnN, n); mxN = fmaxf(mxN, n);
    }
    mnA = wave_min(mnA); mxA = wave_max(mxA);
    mnN = wave_min(mnN); mxN = wave_max(mxN);
    __shared__ float red[4][4];
    __shared__ float bc[4];
    if (lane == 0) {
        red[wid][0] = mnA; red[wid][1] = mxA;
        red[wid][2] = mnN; red[wid][3] = mxN;
    }
    __syncthreads();
    if (t == 0) {
        float a0 = red[0][0], a1 = red[0][1], a2 = red[0][2], a3 = red[0][3];
        for (int ww = 1; ww < 4; ww++) {
            a0 = fminf(a0, red[ww][0]); a1 = fmaxf(a1, red[ww][1]);
            a2 = fminf(a2, red[ww][2]); a3 = fmaxf(a3, red[ww][3]);
        }
        bc[0] = a0; bc[1] = a1; bc[2] = a2; bc[3] = a3;
    }
    __syncthreads();
    float fmnA = bc[0], fmxA = bc[1], fmnN = bc[2], fmxN = bc[3];
    float invA = 1.0f / (fmxA - fmnA + EPS);
    float invN = 1.0f / (fmxN - fmnN + EPS);
    for (int i = t; i < 4096; i += 256) {
        float s_aa = (pa[i] - fmnA) * invA;
        float s_an = (pn[i] - fmnN) * invN;
        float fused = 0.8f * s_aa + 0.2f * (1.0f - s_an);
        pseudo[b * 4096 + i] = fused > 0.55f ? 1.0f : 0.0f;
        S_aa_norm[b * 4096 + i] = s_aa;
    }
}

extern "C" void kernel_launch(void* const* d_in, const int* in_sizes, int n_in,
                              void* d_out, int out_size, void* d_ws, size_t ws_size,
                              hipStream_t stream) {
    const float* normal_feats  = (const float*)d_in[0];
    const float* anomaly_feats = (const float*)d_in[1];
    const int*   cls           = (const int*)d_in[2];
    const float* T_emb         = (const float*)d_in[3];
    const float* w_score       = (const float*)d_in[4];
    const float* b_score       = (const float*)d_in[5];
    float* out = (float*)d_out;

    float4* Wt4 = (float4*)d_ws;   // 128 * 15 float4 = 30 KiB

    kprep<<<1, 960, 0, stream>>>(T_emb, w_score, Wt4, out + O_TN);

    dim3 gd(1024, 2);
    kdots<<<gd, 256, 0, stream>>>((const float4*)normal_feats,
                                  (const float4*)anomaly_feats,
                                  Wt4, cls, b_score,
                                  out + O_SNN, out + O_PHINA,
                                  out + O_SAN, out + O_SAA,
                                  out + O_PHIOTHER, out + O_SCORES);

    kbatch<<<16, 256, 0, stream>>>(out + O_SAA, out + O_SAN,
                                   out + O_SAANORM, out + O_PSEUDO);
}